// Round 11
// baseline (191.475 us; speedup 1.0000x reference)
//
#include <hip/hip_runtime.h>
#include <cstdint>

// CQAttention: B=32, D=128, Lc=2048, Lq=256, f32 in/out.
// Pipeline (R11):
//   k_cq x2 : cq = Ct@w4C, qq = Qt@w4Q
//   k_tr x2 : bf16 copies: Ct_bf [b][i][d], Cbf [b][d][i],
//             Qtw [b][j][d] (w4mlu folded), Qbf [b][d][j]
//   k_MT    : single pass (exp(v-20) const shift): S^T + exp -> LDS P^T ->
//             MT = C @ P2 / colsum -> bf16.
//   k_PAB   : fused row-softmax + A/Bt GEMMs. R11: 256B-segment epilogue.
//             R10's direct D-frag stores emitted 16x64B scattered segments
//             per wave instr (partial 128B-line writes -> ~2x write BW loss;
//             k_AB-part pinned at ~78us with all util counters <8%). Now:
//             per d-half, stage scaled cA/cB into LT_A/LT_B [64][68] f32,
//             then stream stores where each wave instr covers 4 d-rows x
//             256B contiguous (C reload uses the same pattern). Live set
//             per half: afr(32)+8xf32x4 - no spill (R3-R6 lesson).
// Bt = S1 @ (S2^T @ Ct) associativity rewrite avoids the Lc x Lc matrix.

#define NB 32
#define ND 128
#define NLC 2048
#define NLQ 256
#define FNEG (-1.0e30f)
#define ESHIFT 20.0f

typedef __attribute__((ext_vector_type(8))) short bf16x8;
typedef __attribute__((ext_vector_type(4))) float f32x4;
#define MFMA16(a, b, c) __builtin_amdgcn_mfma_f32_16x16x32_bf16(a, b, c, 0, 0, 0)

__device__ __forceinline__ short f2bf(float x) {
  union { float f; unsigned u; } v; v.f = x;
  unsigned r = (v.u + 0x7FFFu + ((v.u >> 16) & 1u)) >> 16;
  return (short)r;
}
__device__ __forceinline__ float bf2f(short x) {
  union { unsigned u; float f; } v; v.u = ((unsigned)(unsigned short)x) << 16;
  return v.f;
}

// ---------------- cq / qq : out[g] = sum_d In[b,d,i] * w[d] ----------------
__global__ __launch_bounds__(256) void k_cq(const float* __restrict__ In,
                                            const float* __restrict__ w,
                                            float* __restrict__ outv, int L) {
  int g = blockIdx.x * 256 + threadIdx.x;
  int b = g / L, i = g - b * L;
  const float* p = In + (size_t)b * ND * L + i;
  float s = 0.f;
#pragma unroll 16
  for (int d = 0; d < ND; ++d) s = fmaf(p[(size_t)d * L], w[d], s);
  outv[g] = s;
}

// ---------------- bf16 copies: transposed (scaled) + natural ---------------
__global__ __launch_bounds__(256) void k_tr(const float* __restrict__ in,
                                            const float* __restrict__ wvec,
                                            short* __restrict__ outT,
                                            short* __restrict__ outN, int L) {
  __shared__ float T[32][66];
  const int b = blockIdx.z, d0 = blockIdx.y * 32, i0 = blockIdx.x * 64;
  const int t = threadIdx.x;
#pragma unroll
  for (int rr = 0; rr < 2; ++rr) {
    int idx = t + rr * 256;
    int dd = idx >> 4, c4 = idx & 15;
    const float* src = in + ((size_t)b * ND + d0 + dd) * L + i0 + c4 * 4;
    float4 v = *(const float4*)src;
    T[dd][c4 * 4 + 0] = v.x;
    T[dd][c4 * 4 + 1] = v.y;
    T[dd][c4 * 4 + 2] = v.z;
    T[dd][c4 * 4 + 3] = v.w;
    if (outN) {
      short4 o;
      o.x = f2bf(v.x); o.y = f2bf(v.y); o.z = f2bf(v.z); o.w = f2bf(v.w);
      *(short4*)(outN + ((size_t)b * ND + d0 + dd) * L + i0 + c4 * 4) = o;
    }
  }
  __syncthreads();
  const int i = t >> 2, seg = t & 3;
  bf16x8 pack;
#pragma unroll
  for (int k = 0; k < 8; ++k) {
    int d = seg * 8 + k;
    float x = T[d][i];
    if (wvec) x *= wvec[d0 + d];
    pack[k] = f2bf(x);
  }
  *(bf16x8*)(outT + ((size_t)b * L + i0 + i) * ND + d0 + seg * 8) = pack;
}

// ---------------- k_MT: MT[b,d,q] = sum_i softmax_col(S)[i,q] * C[b,d,i] ---
// grid (NLQ/32, NB), 512 thr (8 waves). Single pass (const-shift exp).
__global__ __launch_bounds__(512) void k_MT(const short* __restrict__ Ctbf,
                                            const short* __restrict__ Qtw,
                                            const short* __restrict__ Cbf,
                                            const int* __restrict__ Cmask,
                                            const float* __restrict__ cq,
                                            const float* __restrict__ qq,
                                            const float* __restrict__ bias,
                                            short* __restrict__ MTbf) {
  __shared__ short PTs[32 * 136];   // P2^T bf16 [q 32][i-chunk 128], pad->136
  __shared__ float cspart[8][32];
  __shared__ float bc[32];
  const int b = blockIdx.y, qt = blockIdx.x * 32;
  const int tid = threadIdx.x;
  const int w = tid >> 6, l = tid & 63, lm = l & 15, lk = l >> 4;
  const int qsub = w & 1, ipair = w >> 1;
  const float bv = bias[0];

  bf16x8 aq[4];
  const short* Qrow = Qtw + ((size_t)b * NLQ + qt + qsub * 16 + lm) * ND + lk * 8;
#pragma unroll
  for (int kk = 0; kk < 4; ++kk) aq[kk] = *(const bf16x8*)(Qrow + kk * 32);
  float qqv[4];
#pragma unroll
  for (int r = 0; r < 4; ++r) qqv[r] = qq[b * NLQ + qt + qsub * 16 + lk * 4 + r];

  float csacc[4] = {0.f, 0.f, 0.f, 0.f};
  f32x4 accMT[2] = {{0.f, 0.f, 0.f, 0.f}, {0.f, 0.f, 0.f, 0.f}};
  for (int i0 = 0; i0 < NLC; i0 += 128) {
#pragma unroll
    for (int t2 = 0; t2 < 2; ++t2) {
      const int isub = ipair * 2 + t2;
      const int iCol = i0 + isub * 16 + lm;
      const short* Crow = Ctbf + ((size_t)b * NLC + iCol) * ND + lk * 8;
      f32x4 c = {0.f, 0.f, 0.f, 0.f};
#pragma unroll
      for (int kk = 0; kk < 4; ++kk)
        c = MFMA16(aq[kk], *(const bf16x8*)(Crow + kk * 32), c);
      const float cqb = cq[b * NLC + iCol] + bv;
      const int cm = Cmask[b * NLC + iCol];
#pragma unroll
      for (int r = 0; r < 4; ++r) {
        float s = c[r] + cqb + qqv[r];
        float v = cm ? s : s + FNEG;
        float p = __expf(v - ESHIFT);
        csacc[r] += p;
        PTs[(qsub * 16 + lk * 4 + r) * 136 + isub * 16 + lm] = f2bf(p);
      }
    }
    __syncthreads();
    // MT GEMM: A[m=d]=Cbf (i-contig), B[k=i][n=q]=P^T from LDS
    const short* Arow = Cbf + ((size_t)b * ND + w * 16 + lm) * NLC + i0 + lk * 8;
#pragma unroll
    for (int ks = 0; ks < 4; ++ks) {
      bf16x8 a = *(const bf16x8*)(Arow + ks * 32);
#pragma unroll
      for (int qs = 0; qs < 2; ++qs) {
        bf16x8 bb = *(const bf16x8*)&PTs[(qs * 16 + lm) * 136 + ks * 32 + lk * 8];
        accMT[qs] = MFMA16(a, bb, accMT[qs]);
      }
    }
    __syncthreads();
  }
  // colsum reduce
#pragma unroll
  for (int off = 1; off < 16; off <<= 1)
#pragma unroll
    for (int r = 0; r < 4; ++r) csacc[r] += __shfl_xor(csacc[r], off, 64);
  if (lm == 0) {
#pragma unroll
    for (int r = 0; r < 4; ++r) cspart[w][qsub * 16 + lk * 4 + r] = csacc[r];
  }
  __syncthreads();
  if (tid < 32) {
    const int base = (tid >> 4) & 1;
    float s = 0.f;
#pragma unroll
    for (int k2 = 0; k2 < 4; ++k2) s += cspart[k2 * 2 + base][tid];
    bc[tid] = 1.0f / s;
  }
  __syncthreads();
#pragma unroll
  for (int qs = 0; qs < 2; ++qs) {
    const float inv = bc[qs * 16 + lm];
#pragma unroll
    for (int r = 0; r < 4; ++r)
      MTbf[((size_t)b * ND + w * 16 + lk * 4 + r) * NLQ + qt + qs * 16 + lm] =
          f2bf(accMT[qs][r] * inv);
  }
}

// ---------------- k_PAB: fused row-softmax + A/Bt GEMMs + 256B stores ------
// 1D grid 1024 blocks (XCD-bijective swizzle). 256 thr (4 waves).
// Phase 1: S = Ct@Qtw' + cq+qq+bias via MFMA; raw p = exp(v-ESHIFT) -> bf16
//   LDS PTs [64][264]; rowsum -> rs[64] (1/sum).
// Phase 2: afr[8] from PTs; per d-half: {4x n0: 2x8 MFMA, stage scaled to
//   LT_A/LT_B [64][68]} -> sync -> stream stores (4 d-rows x 256B per wave
//   instr for all 4 streams; C reloaded with the same coalesced pattern).
__global__ __launch_bounds__(256) void k_PAB(const float* __restrict__ C,
                                             const short* __restrict__ Ctbf,
                                             const short* __restrict__ Qtw,
                                             const short* __restrict__ Qbf,
                                             const short* __restrict__ MTbf,
                                             const int* __restrict__ Qmask,
                                             const float* __restrict__ cq,
                                             const float* __restrict__ qq,
                                             const float* __restrict__ bias,
                                             float* __restrict__ out) {
  __shared__ __align__(16) char SMEM[64 * 68 * 4 * 2];  // 34816B: PTs / LT_A+LT_B
  short* PTs = (short*)SMEM;                  // [64][264] bf16 (33792B)
  float* LTA = (float*)SMEM;                  // [64][68] f32
  float* LTB = LTA + 64 * 68;                 // [64][68] f32
  __shared__ float rs[64];
  const int flat = blockIdx.x;                 // 1024 = 8*128 exactly
  const int swz = (flat & 7) * 128 + (flat >> 3);
  const int b = swz >> 5, it = (swz & 31) * 64;
  const int tid = threadIdx.x;
  const int wi = tid >> 6, l = tid & 63, lm = l & 15, lk = l >> 4;

  // ---- phase 1: S via MFMA -> exp -> LDS (raw p), rowsum ----
  {
    bf16x8 aS[4];
    const short* Crow = Ctbf + ((size_t)b * NLC + it + wi * 16 + lm) * ND + lk * 8;
#pragma unroll
    for (int kk = 0; kk < 4; ++kk) aS[kk] = *(const bf16x8*)(Crow + kk * 32);
    const float bv = bias[0];
    float cqb[4];
#pragma unroll
    for (int r = 0; r < 4; ++r) cqb[r] = cq[b * NLC + it + wi * 16 + lk * 4 + r] + bv;
    const short* Qt0 = Qtw + (size_t)b * NLQ * ND;

    float rsum[4] = {0.f, 0.f, 0.f, 0.f};
#pragma unroll
    for (int js = 0; js < 16; ++js) {
      const short* Qrow = Qt0 + (size_t)(js * 16 + lm) * ND + lk * 8;
      f32x4 c = {0.f, 0.f, 0.f, 0.f};
#pragma unroll
      for (int kk = 0; kk < 4; ++kk)
        c = MFMA16(aS[kk], *(const bf16x8*)(Qrow + kk * 32), c);
      const int j = js * 16 + lm;
      const float qv = qq[b * NLQ + j];
      const int qm = Qmask[b * NLQ + j];
#pragma unroll
      for (int r = 0; r < 4; ++r) {
        float s = c[r] + cqb[r] + qv;
        float v = qm ? s : s + FNEG;
        float p = __expf(v - ESHIFT);
        rsum[r] += p;
        PTs[(wi * 16 + lk * 4 + r) * 264 + js * 16 + lm] = f2bf(p);
      }
    }
#pragma unroll
    for (int off = 1; off < 16; off <<= 1)
#pragma unroll
      for (int r = 0; r < 4; ++r) rsum[r] += __shfl_xor(rsum[r], off, 64);
    if (lm == 0) {
#pragma unroll
      for (int r = 0; r < 4; ++r) rs[wi * 16 + lk * 4 + r] = 1.0f / rsum[r];
    }
  }
  __syncthreads();

  // ---- phase 2: afr (raw p) + invr from LDS ----
  bf16x8 afr[8];
#pragma unroll
  for (int kk = 0; kk < 8; ++kk)
    afr[kk] = *(const bf16x8*)&PTs[(wi * 16 + lm) * 264 + kk * 32 + lk * 8];
  float invr[4];
#pragma unroll
  for (int r = 0; r < 4; ++r) invr[r] = rs[wi * 16 + lk * 4 + r];
  __syncthreads();  // all PTs reads done before LT overwrite

  const short* Qp = Qbf + (size_t)b * ND * NLQ;
  const short* Mp = MTbf + (size_t)b * ND * NLQ;
  const float* Cb = C + (size_t)b * ND * NLC;
  float* ob = out + (size_t)b * 4 * ND * NLC;
  const int g = tid >> 4, c = tid & 15;   // store-phase thread mapping

#pragma unroll
  for (int dh = 0; dh < 2; ++dh) {
    if (dh) __syncthreads();  // LT reads of previous half done
    // compute + stage 4 n0 tiles of this d-half
#pragma unroll
    for (int n0i = 0; n0i < 4; ++n0i) {
      const int n0 = dh * 4 + n0i;
      const short* BpQ = Qp + (size_t)(n0 * 16 + lm) * NLQ + lk * 8;
      const short* BpM = Mp + (size_t)(n0 * 16 + lm) * NLQ + lk * 8;
      f32x4 cA = {0.f, 0.f, 0.f, 0.f};
      f32x4 cB = {0.f, 0.f, 0.f, 0.f};
#pragma unroll
      for (int kk = 0; kk < 8; ++kk) {
        cA = MFMA16(afr[kk], *(const bf16x8*)(BpQ + kk * 32), cA);
        cB = MFMA16(afr[kk], *(const bf16x8*)(BpM + kk * 32), cB);
      }
      const int dl = n0i * 16 + lm;
      const int il = wi * 16 + lk * 4;
#pragma unroll
      for (int r = 0; r < 4; ++r) {
        LTA[dl * 68 + il + r] = cA[r] * invr[r];
        LTB[dl * 68 + il + r] = cB[r] * invr[r];
      }
    }
    __syncthreads();
    // stream stores: wave instr = 4 d-rows x 256B contiguous
#pragma unroll
    for (int s = 0; s < 4; ++s) {
      const int dl = g * 4 + s;            // 0..63
      const int dg = dh * 64 + dl;
      float4 av = *(const float4*)&LTA[dl * 68 + c * 4];
      float4 bv4 = *(const float4*)&LTB[dl * 68 + c * 4];
      float4 ct = *(const float4*)&Cb[(size_t)dg * NLC + it + c * 4];
      float4 ca, cb;
      ca.x = ct.x * av.x; ca.y = ct.y * av.y; ca.z = ct.z * av.z; ca.w = ct.w * av.w;
      cb.x = ct.x * bv4.x; cb.y = ct.y * bv4.y; cb.z = ct.z * bv4.z; cb.w = ct.w * bv4.w;
      float* o0 = ob + (size_t)dg * NLC + it + c * 4;
      *(float4*)o0 = ct;
      *(float4*)(o0 + (size_t)128 * NLC) = av;
      *(float4*)(o0 + (size_t)256 * NLC) = ca;
      *(float4*)(o0 + (size_t)384 * NLC) = cb;
    }
  }
}

// ---------------------------------------------------------------------------
extern "C" void kernel_launch(void* const* d_in, const int* in_sizes, int n_in,
                              void* d_out, int out_size, void* d_ws, size_t ws_size,
                              hipStream_t stream) {
  const float* C = (const float*)d_in[0];
  const float* Q = (const float*)d_in[1];
  const int* Cmask = (const int*)d_in[2];
  const int* Qmask = (const int*)d_in[3];
  const float* w4C = (const float*)d_in[4];
  const float* w4Q = (const float*)d_in[5];
  const float* w4mlu = (const float*)d_in[6];
  const float* bias = (const float*)d_in[7];
  float* out = (float*)d_out;

  short* Ctbf = (short*)d_ws;                          // [b][Lc][D]
  short* Cbf = Ctbf + (size_t)NB * NLC * ND;           // [b][D][Lc]
  short* Qtw = Cbf + (size_t)NB * NLC * ND;            // [b][Lq][D] (w4mlu folded)
  short* Qbf = Qtw + (size_t)NB * NLQ * ND;            // [b][D][Lq]
  short* MTbf = Qbf + (size_t)NB * NLQ * ND;           // [b][D][Lq]
  float* cq = (float*)(MTbf + (size_t)NB * ND * NLQ);
  float* qq = cq + NB * NLC;
  size_t need = (size_t)(qq + NB * NLQ - (float*)d_ws) * sizeof(float);
  if (ws_size < need) return;  // fail loudly rather than corrupt

  k_cq<<<NB * NLC / 256, 256, 0, stream>>>(C, w4C, cq, NLC);
  k_cq<<<NB * NLQ / 256, 256, 0, stream>>>(Q, w4Q, qq, NLQ);
  k_tr<<<dim3(NLC / 64, ND / 32, NB), 256, 0, stream>>>(C, nullptr, Ctbf, Cbf, NLC);
  k_tr<<<dim3(NLQ / 64, ND / 32, NB), 256, 0, stream>>>(Q, w4mlu, Qtw, Qbf, NLQ);
  k_MT<<<dim3(NLQ / 32, NB), 512, 0, stream>>>(Ctbf, Qtw, Cbf, Cmask, cq, qq, bias, MTbf);
  k_PAB<<<1024, 256, 0, stream>>>(C, Ctbf, Qtw, Qbf, MTbf, Qmask, cq, qq, bias, out);
}

// Round 12
// 148.994 us; speedup vs baseline: 1.2851x; 1.2851x over previous
//
#include <hip/hip_runtime.h>
#include <cstdint>

// CQAttention: B=32, D=128, Lc=2048, Lq=256, f32 in/out.
// Pipeline (R12):
//   k_cq x2 : cq = Ct@w4C, qq = Qt@w4Q
//   k_tr x2 : bf16 copies: Ct_bf [b][i][d], Cbf [b][d][i],
//             Qtw [b][j][d] (w4mlu folded), Qbf [b][d][j]
//   k_MT    : single pass (exp(v-20) const shift): S^T + exp -> LDS P^T ->
//             MT = C @ P2 / colsum -> bf16.
//   k_PAB   : fused row-softmax + A/Bt GEMMs. R12: double-buffered LDS
//             B-panel staging. R7-R11 invariant: every wave loaded the
//             SAME B-fragments (no wi in the address) as 16x64B scattered
//             segments -> 2048 L1 transactions/wave, latency-bound at 42%
//             occupancy (~78us floor; store-granularity change was null).
//             Now: per n0, 256 threads stage Q+M panels (16KB) into the
//             dead PTs LDS (2x16KB double buffer), coalesced 4-row x 512B
//             chunks, issue-early/write-late across previous tile's MFMA;
//             XOR-swizzled (col16 ^= row&7) for conflict-free ds r/w.
//             Direct D-frag stores (R11 256B-segment epilogue was null);
//             rowsum scale kept in-register (rs[] LDS eliminated).
// Bt = S1 @ (S2^T @ Ct) associativity rewrite avoids the Lc x Lc matrix.

#define NB 32
#define ND 128
#define NLC 2048
#define NLQ 256
#define FNEG (-1.0e30f)
#define ESHIFT 20.0f

typedef __attribute__((ext_vector_type(8))) short bf16x8;
typedef __attribute__((ext_vector_type(4))) float f32x4;
#define MFMA16(a, b, c) __builtin_amdgcn_mfma_f32_16x16x32_bf16(a, b, c, 0, 0, 0)

__device__ __forceinline__ short f2bf(float x) {
  union { float f; unsigned u; } v; v.f = x;
  unsigned r = (v.u + 0x7FFFu + ((v.u >> 16) & 1u)) >> 16;
  return (short)r;
}
__device__ __forceinline__ float bf2f(short x) {
  union { unsigned u; float f; } v; v.u = ((unsigned)(unsigned short)x) << 16;
  return v.f;
}

// ---------------- cq / qq : out[g] = sum_d In[b,d,i] * w[d] ----------------
__global__ __launch_bounds__(256) void k_cq(const float* __restrict__ In,
                                            const float* __restrict__ w,
                                            float* __restrict__ outv, int L) {
  int g = blockIdx.x * 256 + threadIdx.x;
  int b = g / L, i = g - b * L;
  const float* p = In + (size_t)b * ND * L + i;
  float s = 0.f;
#pragma unroll 16
  for (int d = 0; d < ND; ++d) s = fmaf(p[(size_t)d * L], w[d], s);
  outv[g] = s;
}

// ---------------- bf16 copies: transposed (scaled) + natural ---------------
__global__ __launch_bounds__(256) void k_tr(const float* __restrict__ in,
                                            const float* __restrict__ wvec,
                                            short* __restrict__ outT,
                                            short* __restrict__ outN, int L) {
  __shared__ float T[32][66];
  const int b = blockIdx.z, d0 = blockIdx.y * 32, i0 = blockIdx.x * 64;
  const int t = threadIdx.x;
#pragma unroll
  for (int rr = 0; rr < 2; ++rr) {
    int idx = t + rr * 256;
    int dd = idx >> 4, c4 = idx & 15;
    const float* src = in + ((size_t)b * ND + d0 + dd) * L + i0 + c4 * 4;
    float4 v = *(const float4*)src;
    T[dd][c4 * 4 + 0] = v.x;
    T[dd][c4 * 4 + 1] = v.y;
    T[dd][c4 * 4 + 2] = v.z;
    T[dd][c4 * 4 + 3] = v.w;
    if (outN) {
      short4 o;
      o.x = f2bf(v.x); o.y = f2bf(v.y); o.z = f2bf(v.z); o.w = f2bf(v.w);
      *(short4*)(outN + ((size_t)b * ND + d0 + dd) * L + i0 + c4 * 4) = o;
    }
  }
  __syncthreads();
  const int i = t >> 2, seg = t & 3;
  bf16x8 pack;
#pragma unroll
  for (int k = 0; k < 8; ++k) {
    int d = seg * 8 + k;
    float x = T[d][i];
    if (wvec) x *= wvec[d0 + d];
    pack[k] = f2bf(x);
  }
  *(bf16x8*)(outT + ((size_t)b * L + i0 + i) * ND + d0 + seg * 8) = pack;
}

// ---------------- k_MT: MT[b,d,q] = sum_i softmax_col(S)[i,q] * C[b,d,i] ---
// grid (NLQ/32, NB), 512 thr (8 waves). Single pass (const-shift exp).
__global__ __launch_bounds__(512) void k_MT(const short* __restrict__ Ctbf,
                                            const short* __restrict__ Qtw,
                                            const short* __restrict__ Cbf,
                                            const int* __restrict__ Cmask,
                                            const float* __restrict__ cq,
                                            const float* __restrict__ qq,
                                            const float* __restrict__ bias,
                                            short* __restrict__ MTbf) {
  __shared__ short PTs[32 * 136];   // P2^T bf16 [q 32][i-chunk 128], pad->136
  __shared__ float cspart[8][32];
  __shared__ float bc[32];
  const int b = blockIdx.y, qt = blockIdx.x * 32;
  const int tid = threadIdx.x;
  const int w = tid >> 6, l = tid & 63, lm = l & 15, lk = l >> 4;
  const int qsub = w & 1, ipair = w >> 1;
  const float bv = bias[0];

  bf16x8 aq[4];
  const short* Qrow = Qtw + ((size_t)b * NLQ + qt + qsub * 16 + lm) * ND + lk * 8;
#pragma unroll
  for (int kk = 0; kk < 4; ++kk) aq[kk] = *(const bf16x8*)(Qrow + kk * 32);
  float qqv[4];
#pragma unroll
  for (int r = 0; r < 4; ++r) qqv[r] = qq[b * NLQ + qt + qsub * 16 + lk * 4 + r];

  float csacc[4] = {0.f, 0.f, 0.f, 0.f};
  f32x4 accMT[2] = {{0.f, 0.f, 0.f, 0.f}, {0.f, 0.f, 0.f, 0.f}};
  for (int i0 = 0; i0 < NLC; i0 += 128) {
#pragma unroll
    for (int t2 = 0; t2 < 2; ++t2) {
      const int isub = ipair * 2 + t2;
      const int iCol = i0 + isub * 16 + lm;
      const short* Crow = Ctbf + ((size_t)b * NLC + iCol) * ND + lk * 8;
      f32x4 c = {0.f, 0.f, 0.f, 0.f};
#pragma unroll
      for (int kk = 0; kk < 4; ++kk)
        c = MFMA16(aq[kk], *(const bf16x8*)(Crow + kk * 32), c);
      const float cqb = cq[b * NLC + iCol] + bv;
      const int cm = Cmask[b * NLC + iCol];
#pragma unroll
      for (int r = 0; r < 4; ++r) {
        float s = c[r] + cqb + qqv[r];
        float v = cm ? s : s + FNEG;
        float p = __expf(v - ESHIFT);
        csacc[r] += p;
        PTs[(qsub * 16 + lk * 4 + r) * 136 + isub * 16 + lm] = f2bf(p);
      }
    }
    __syncthreads();
    // MT GEMM: A[m=d]=Cbf (i-contig), B[k=i][n=q]=P^T from LDS
    const short* Arow = Cbf + ((size_t)b * ND + w * 16 + lm) * NLC + i0 + lk * 8;
#pragma unroll
    for (int ks = 0; ks < 4; ++ks) {
      bf16x8 a = *(const bf16x8*)(Arow + ks * 32);
#pragma unroll
      for (int qs = 0; qs < 2; ++qs) {
        bf16x8 bb = *(const bf16x8*)&PTs[(qs * 16 + lm) * 136 + ks * 32 + lk * 8];
        accMT[qs] = MFMA16(a, bb, accMT[qs]);
      }
    }
    __syncthreads();
  }
  // colsum reduce
#pragma unroll
  for (int off = 1; off < 16; off <<= 1)
#pragma unroll
    for (int r = 0; r < 4; ++r) csacc[r] += __shfl_xor(csacc[r], off, 64);
  if (lm == 0) {
#pragma unroll
    for (int r = 0; r < 4; ++r) cspart[w][qsub * 16 + lk * 4 + r] = csacc[r];
  }
  __syncthreads();
  if (tid < 32) {
    const int base = (tid >> 4) & 1;
    float s = 0.f;
#pragma unroll
    for (int k2 = 0; k2 < 4; ++k2) s += cspart[k2 * 2 + base][tid];
    bc[tid] = 1.0f / s;
  }
  __syncthreads();
#pragma unroll
  for (int qs = 0; qs < 2; ++qs) {
    const float inv = bc[qs * 16 + lm];
#pragma unroll
    for (int r = 0; r < 4; ++r)
      MTbf[((size_t)b * ND + w * 16 + lk * 4 + r) * NLQ + qt + qs * 16 + lm] =
          f2bf(accMT[qs][r] * inv);
  }
}

// ---------------- k_PAB: fused softmax + A/Bt GEMMs, LDS B-staging ---------
// 1D grid 1024 blocks (XCD-bijective swizzle). 256 thr (4 waves).
// Phase 1: S = Ct@Qtw' + cq+qq+bias via MFMA; raw p = exp(v-ESHIFT) -> bf16
//   LDS PTs [64][264]; rowsum kept in-register (invr).
// Phase 2: afr[8] from PTs -> PTs LDS becomes 2x16KB B-panel double buffer.
//   Per n0: coop-stage Q+M panels (coalesced), MFMA from swizzled LDS,
//   direct D-frag stores {Ct, A, Ct*A, Ct*Bt}.
__global__ __launch_bounds__(256) void k_PAB(const float* __restrict__ C,
                                             const short* __restrict__ Ctbf,
                                             const short* __restrict__ Qtw,
                                             const short* __restrict__ Qbf,
                                             const short* __restrict__ MTbf,
                                             const int* __restrict__ Qmask,
                                             const float* __restrict__ cq,
                                             const float* __restrict__ qq,
                                             const float* __restrict__ bias,
                                             float* __restrict__ out) {
  __shared__ __align__(16) char SMEM[64 * 264 * 2];  // 33792B: PTs, then 2x16KB B-stage
  short* PTs = (short*)SMEM;
  char* Bst = SMEM;
  const int flat = blockIdx.x;                 // 1024 = 8*128 exactly
  const int swz = (flat & 7) * 128 + (flat >> 3);
  const int b = swz >> 5, it = (swz & 31) * 64;
  const int tid = threadIdx.x;
  const int wi = tid >> 6, l = tid & 63, lm = l & 15, lk = l >> 4;

  // ---- phase 1: S via MFMA -> exp -> LDS (raw p), rowsum in-register ----
  float invr[4];
  {
    bf16x8 aS[4];
    const short* Crow = Ctbf + ((size_t)b * NLC + it + wi * 16 + lm) * ND + lk * 8;
#pragma unroll
    for (int kk = 0; kk < 4; ++kk) aS[kk] = *(const bf16x8*)(Crow + kk * 32);
    const float bv = bias[0];
    float cqb[4];
#pragma unroll
    for (int r = 0; r < 4; ++r) cqb[r] = cq[b * NLC + it + wi * 16 + lk * 4 + r] + bv;
    const short* Qt0 = Qtw + (size_t)b * NLQ * ND;

    float rsum[4] = {0.f, 0.f, 0.f, 0.f};
#pragma unroll
    for (int js = 0; js < 16; ++js) {
      const short* Qrow = Qt0 + (size_t)(js * 16 + lm) * ND + lk * 8;
      f32x4 c = {0.f, 0.f, 0.f, 0.f};
#pragma unroll
      for (int kk = 0; kk < 4; ++kk)
        c = MFMA16(aS[kk], *(const bf16x8*)(Qrow + kk * 32), c);
      const int j = js * 16 + lm;
      const float qv = qq[b * NLQ + j];
      const int qm = Qmask[b * NLQ + j];
#pragma unroll
      for (int r = 0; r < 4; ++r) {
        float s = c[r] + cqb[r] + qv;
        float v = qm ? s : s + FNEG;
        float p = __expf(v - ESHIFT);
        rsum[r] += p;
        PTs[(wi * 16 + lk * 4 + r) * 264 + js * 16 + lm] = f2bf(p);
      }
    }
#pragma unroll
    for (int off = 1; off < 16; off <<= 1)
#pragma unroll
      for (int r = 0; r < 4; ++r) rsum[r] += __shfl_xor(rsum[r], off, 64);
#pragma unroll
    for (int r = 0; r < 4; ++r) invr[r] = 1.0f / rsum[r];
  }
  __syncthreads();

  // ---- afr (raw p rows) from PTs ----
  bf16x8 afr[8];
#pragma unroll
  for (int kk = 0; kk < 8; ++kk)
    afr[kk] = *(const bf16x8*)&PTs[(wi * 16 + lm) * 264 + kk * 32 + lk * 8];
  __syncthreads();  // all PTs reads done before B-staging overwrite

  // ---- phase 2: double-buffered B-panel staging + MFMA + direct stores ----
  const short* Qp = Qbf + (size_t)b * ND * NLQ;
  const short* Mp = MTbf + (size_t)b * ND * NLQ;
  const float* Cb = C + (size_t)b * ND * NLC;
  float* ob = out + (size_t)b * 4 * ND * NLC;
  const int iB = it + wi * 16 + lk * 4;

  // staging thread mapping: 16 rows x 16 cols of 32B (per panel, 8KB)
  const int srow = tid >> 4, scol = tid & 15;
  const int wsw0 = (((scol * 2) ^ (srow & 7)) << 4);
  const int wsw1 = (((scol * 2 + 1) ^ (srow & 7)) << 4);
  const short* qsrc = Qp + (size_t)srow * NLQ + scol * 16;
  const short* msrc = Mp + (size_t)srow * NLQ + scol * 16;
  bf16x8 sq0, sq1, sm0, sm1;

#define LOADN(n0) { \
    const short* q_ = qsrc + (size_t)(n0) * 16 * NLQ; \
    const short* m_ = msrc + (size_t)(n0) * 16 * NLQ; \
    sq0 = *(const bf16x8*)q_;  sq1 = *(const bf16x8*)(q_ + 8); \
    sm0 = *(const bf16x8*)m_;  sm1 = *(const bf16x8*)(m_ + 8); }
#define WRITEN(buf) { \
    char* base_ = Bst + (buf) * 16384 + srow * 512; \
    *(bf16x8*)(base_ + wsw0) = sq0; *(bf16x8*)(base_ + wsw1) = sq1; \
    *(bf16x8*)(base_ + 8192 + wsw0) = sm0; *(bf16x8*)(base_ + 8192 + wsw1) = sm1; }

  LOADN(0); WRITEN(0);
  __syncthreads();
#pragma unroll
  for (int n0 = 0; n0 < 8; ++n0) {
    if (n0 < 7) LOADN(n0 + 1);                 // issue next-tile loads early
    const int d = n0 * 16 + lm;
    float4 ct = *(const float4*)&Cb[(size_t)d * NLC + iB];  // independent, early
    const char* bq = Bst + (n0 & 1) * 16384 + lm * 512;
    f32x4 cA = {0.f, 0.f, 0.f, 0.f};
    f32x4 cB = {0.f, 0.f, 0.f, 0.f};
#pragma unroll
    for (int kk = 0; kk < 8; ++kk) {
      const int so = (((kk * 4 + lk) ^ (lm & 7)) << 4);
      cA = MFMA16(afr[kk], *(const bf16x8*)(bq + so), cA);
      cB = MFMA16(afr[kk], *(const bf16x8*)(bq + 8192 + so), cB);
    }
    if (n0 < 7) {
      WRITEN((n0 + 1) & 1);                    // write-late into other buffer
      __syncthreads();
    }
    float4 av, ca, cb;
    av.x = cA[0] * invr[0]; av.y = cA[1] * invr[1];
    av.z = cA[2] * invr[2]; av.w = cA[3] * invr[3];
    ca.x = ct.x * av.x; ca.y = ct.y * av.y; ca.z = ct.z * av.z; ca.w = ct.w * av.w;
    cb.x = ct.x * cB[0] * invr[0]; cb.y = ct.y * cB[1] * invr[1];
    cb.z = ct.z * cB[2] * invr[2]; cb.w = ct.w * cB[3] * invr[3];
    float* o0 = ob + (size_t)d * NLC + iB;
    *(float4*)o0 = ct;
    *(float4*)(o0 + (size_t)128 * NLC) = av;
    *(float4*)(o0 + (size_t)256 * NLC) = ca;
    *(float4*)(o0 + (size_t)384 * NLC) = cb;
  }
#undef LOADN
#undef WRITEN
}

// ---------------------------------------------------------------------------
extern "C" void kernel_launch(void* const* d_in, const int* in_sizes, int n_in,
                              void* d_out, int out_size, void* d_ws, size_t ws_size,
                              hipStream_t stream) {
  const float* C = (const float*)d_in[0];
  const float* Q = (const float*)d_in[1];
  const int* Cmask = (const int*)d_in[2];
  const int* Qmask = (const int*)d_in[3];
  const float* w4C = (const float*)d_in[4];
  const float* w4Q = (const float*)d_in[5];
  const float* w4mlu = (const float*)d_in[6];
  const float* bias = (const float*)d_in[7];
  float* out = (float*)d_out;

  short* Ctbf = (short*)d_ws;                          // [b][Lc][D]
  short* Cbf = Ctbf + (size_t)NB * NLC * ND;           // [b][D][Lc]
  short* Qtw = Cbf + (size_t)NB * NLC * ND;            // [b][Lq][D] (w4mlu folded)
  short* Qbf = Qtw + (size_t)NB * NLQ * ND;            // [b][D][Lq]
  short* MTbf = Qbf + (size_t)NB * NLQ * ND;           // [b][D][Lq]
  float* cq = (float*)(MTbf + (size_t)NB * ND * NLQ);
  float* qq = cq + NB * NLC;
  size_t need = (size_t)(qq + NB * NLQ - (float*)d_ws) * sizeof(float);
  if (ws_size < need) return;  // fail loudly rather than corrupt

  k_cq<<<NB * NLC / 256, 256, 0, stream>>>(C, w4C, cq, NLC);
  k_cq<<<NB * NLQ / 256, 256, 0, stream>>>(Q, w4Q, qq, NLQ);
  k_tr<<<dim3(NLC / 64, ND / 32, NB), 256, 0, stream>>>(C, nullptr, Ctbf, Cbf, NLC);
  k_tr<<<dim3(NLQ / 64, ND / 32, NB), 256, 0, stream>>>(Q, w4mlu, Qtw, Qbf, NLQ);
  k_MT<<<dim3(NLQ / 32, NB), 512, 0, stream>>>(Ctbf, Qtw, Cbf, Cmask, cq, qq, bias, MTbf);
  k_PAB<<<1024, 256, 0, stream>>>(C, Ctbf, Qtw, Qbf, MTbf, Qmask, cq, qq, bias, out);
}